// Round 12
// baseline (992.815 us; speedup 1.0000x reference)
//
#include <hip/hip_runtime.h>

typedef __bf16 bf16_t;
typedef __attribute__((ext_vector_type(8))) __bf16 bf16x8;
typedef __attribute__((ext_vector_type(4))) float f32x4;
typedef __attribute__((ext_vector_type(16))) float f32x16;

#define NH   8
#define DH   64
#define DD   512
#define NPIX 65536   // 256*256

__device__ __forceinline__ unsigned short f2bf(float f) {
  unsigned int u = __builtin_bit_cast(unsigned int, f);
  u += 0x7fffu + ((u >> 16) & 1u);
  return (unsigned short)(u >> 16);
}
__device__ __forceinline__ float bf2f(unsigned short b) {
  return __builtin_bit_cast(float, ((unsigned int)b) << 16);
}
__device__ __forceinline__ unsigned cvtpk(float a, float b) {
  unsigned r;
  asm("v_cvt_pk_bf16_f32 %0, %1, %2" : "=v"(r) : "v"(a), "v"(b));
  return r;
}

__device__ __forceinline__ void gload_lds16(const void* g, void* l) {
  __builtin_amdgcn_global_load_lds(
      (const __attribute__((address_space(1))) void*)(uintptr_t)g,
      (__attribute__((address_space(3))) void*)(uintptr_t)l, 16, 0, 0);
}

// ---------------- elementwise fp32 -> bf16 convert (weights) ----------------
__global__ __launch_bounds__(256) void k_cvt(const float* __restrict__ in,
                                             unsigned short* __restrict__ out, int n4) {
  int i = blockIdx.x * 256 + threadIdx.x;
  if (i >= n4) return;
  float4 v = ((const float4*)in)[i];
  ushort4 o; o.x = f2bf(v.x); o.y = f2bf(v.y); o.z = f2bf(v.z); o.w = f2bf(v.w);
  ((ushort4*)out)[i] = o;
}

// ------------- x [512][65536] f32 -> x^T [65536][512] bf16 ------------------
__global__ __launch_bounds__(256) void k_cvt_transpose(const float* __restrict__ x,
                                                       unsigned short* __restrict__ xt) {
  __shared__ unsigned short Xs[64 * 68];
  int p0 = blockIdx.x * 64, c0 = blockIdx.y * 64;
  int t = threadIdx.x;
  for (int rep = 0; rep < 4; ++rep) {
    int f = rep * 256 + t, i = f >> 4, jj = f & 15;
    float4 v = *(const float4*)(x + (size_t)(c0 + i) * NPIX + p0 + jj * 4);
    ushort4 o; o.x = f2bf(v.x); o.y = f2bf(v.y); o.z = f2bf(v.z); o.w = f2bf(v.w);
    *(ushort4*)(Xs + i * 68 + jj * 4) = o;
  }
  __syncthreads();
  int j = t >> 2, q = t & 3;
  unsigned short* dst = xt + (size_t)(p0 + j) * DD + c0 + q * 16;
  for (int h2 = 0; h2 < 2; ++h2) {
    union { unsigned short u[8]; uint4 v; } pk;
    for (int cc = 0; cc < 8; ++cc) pk.u[cc] = Xs[(q * 16 + h2 * 8 + cc) * 68 + j];
    *(uint4*)(dst + h2 * 8) = pk.v;
  }
}

// -------- FUSED QKV-projection + axial attention, one block per (h-PAIR,fix) -
// Each block processes 2 heads sequentially with cross-head pipelining:
// during head hh's attention phase, head hh+1's first GEMM tile is already
// staged into buf0 (prefetch), and the x-residual float4s are prefetched to
// registers (T14) so their HBM latency hides under attention compute.
// LDS 152 KiB: staging dbuf 2x56K at [0,112K); qkv (Q^T 32K | K^T 32K | V 32K)
// at [56K,152K) (overlays buf1, dead when written; buf0 stays free for the
// cross-head prefetch).
// chunked-XCD remap: the 4 pair-sibling blocks of one fix land on one XCD so
// the shared B-panel is L2-served.
template <int IS_COL>
__global__ __launch_bounds__(512, 2) void k_fused(const unsigned short* __restrict__ panel,
                                                  const unsigned short* __restrict__ Wb,
                                                  const float* __restrict__ bias,
                                                  const float* __restrict__ x,
                                                  unsigned short* __restrict__ outnat,
                                                  unsigned short* __restrict__ outbt) {
  __shared__ unsigned short smem[77824];   // 152 KiB
  const int tid = threadIdx.x, lane = tid & 63, wave = tid >> 6;
  const int l31 = lane & 31, hi = lane >> 5;
  int bid = blockIdx.y * 8 + blockIdx.x;          // grid (8,128) = 1024 blocks
  int lid = (bid & 7) * 128 + (bid >> 3);         // bijective; same fix -> same XCD
  const int hp = lid & 3, fix = lid >> 2;
  const size_t pixbase = (size_t)fix * 256;
  const int wm = wave >> 2, wn = wave & 3;        // 2 x 4 wave grid
  const int i0w = wave * 32;

  const unsigned short* Pbase = panel + pixbase * 512;
  unsigned short* Qt = smem + 28672;              // [256 p][64 c] swz
  unsigned short* Kt = smem + 45056;              // [256 j][64 c] swz
  unsigned short* Vn = smem + 61440;              // [64 d][256 j] swz

  // stage K-tile kt of head hS into buf b: A = W_hS [192][64], B = panel [256][64]
  auto STAGE = [&](int b, int kt, int hS) {
    unsigned short* Ab = smem + b * 28672;
    unsigned short* Bb = Ab + 12288;
#pragma unroll
    for (int it = 0; it < 3; ++it) {       // A: 192 rows x 8 chunks
      int f = it * 512 + tid;
      int row = f >> 3;
      int cc = (f & 7) ^ (row & 7);
      int grow = (row >> 6) * 512 + hS * 64 + (row & 63);
      gload_lds16(Wb + (size_t)grow * 512 + kt * 64 + cc * 8, Ab + f * 8);
    }
#pragma unroll
    for (int it = 0; it < 4; ++it) {       // B: 256 rows x 8 chunks
      int f = it * 512 + tid;
      int row = f >> 3;
      int cc = (f & 7) ^ (row & 7);
      gload_lds16(Pbase + (size_t)row * 512 + kt * 64 + cc * 8, Bb + f * 8);
    }
  };

  float4 xv[2][4];

  STAGE(0, 0, hp * 2);
  for (int hh = 0; hh < 2; ++hh) {
    const int h = hp * 2 + hh;
    asm volatile("s_waitcnt vmcnt(0)" ::: "memory");
    __syncthreads();

    f32x16 acc[3][2] = {};
    int cur = 0;
    for (int kt = 0; kt < 8; ++kt) {
      if (kt < 7) STAGE(cur ^ 1, kt + 1, h);
      const char* Ad = (const char*)smem + cur * 57344;
      const char* Bd = Ad + 24576;
#pragma unroll
      for (int ks = 0; ks < 4; ++ks) {
        bf16x8 afr[3], bfr[2];
#pragma unroll
        for (int mt = 0; mt < 3; ++mt) {
          int r = wm * 96 + mt * 32 + l31;
          afr[mt] = *(const bf16x8*)(Ad + r * 128 + ((ks * 32 + hi * 16) ^ ((r & 7) << 4)));
        }
#pragma unroll
        for (int nt = 0; nt < 2; ++nt) {
          int r = wn * 64 + nt * 32 + l31;
          bfr[nt] = *(const bf16x8*)(Bd + r * 128 + ((ks * 32 + hi * 16) ^ ((r & 7) << 4)));
        }
        __builtin_amdgcn_s_setprio(1);
#pragma unroll
        for (int mt = 0; mt < 3; ++mt)
#pragma unroll
          for (int nt = 0; nt < 2; ++nt)
            acc[mt][nt] = __builtin_amdgcn_mfma_f32_32x32x16_bf16(afr[mt], bfr[nt], acc[mt][nt], 0, 0, 0);
        __builtin_amdgcn_s_setprio(0);
      }
      asm volatile("s_waitcnt vmcnt(0)" ::: "memory");
      __syncthreads();
      cur ^= 1;
    }

    // cross-head prefetch: head h+1's tile 0 into buf0 (free; qkv is at +56K)
    if (hh == 0) STAGE(0, 0, h + 1);

    // qkv epilogue: C row = wm*96 + mt*32 + 8q + 4hi + j, col = wn*64 + nt*32 + l31
#pragma unroll
    for (int mt = 0; mt < 3; ++mt) {
      int rb = wm * 96 + mt * 32 + 4 * hi;
#pragma unroll
      for (int q = 0; q < 4; ++q) {
        int crow = rb + 8 * q;
        int sel = crow >> 6, r64 = crow & 63;
        f32x4 bv = *(const f32x4*)(bias + sel * 512 + h * 64 + r64);
#pragma unroll
        for (int nt = 0; nt < 2; ++nt) {
          int col = wn * 64 + nt * 32 + l31;
          float v0 = acc[mt][nt][q * 4 + 0] + bv.x;
          float v1 = acc[mt][nt][q * 4 + 1] + bv.y;
          float v2 = acc[mt][nt][q * 4 + 2] + bv.z;
          float v3 = acc[mt][nt][q * 4 + 3] + bv.w;
          if (sel < 2) {                   // q,k -> transposed [p][c]
            ushort4 pk;
            pk.x = f2bf(v0); pk.y = f2bf(v1); pk.z = f2bf(v2); pk.w = f2bf(v3);
            char* base = (char*)(sel ? Kt : Qt);
            *(ushort4*)(base + col * 128 + ((r64 * 2) ^ ((col & 7) << 4))) = pk;
          } else {                         // v -> natural [d][j]
            char* base = (char*)Vn;
            *(unsigned short*)(base + (r64 + 0) * 512 + ((col * 2) ^ (((r64 + 0) & 7) << 4))) = f2bf(v0);
            *(unsigned short*)(base + (r64 + 1) * 512 + ((col * 2) ^ (((r64 + 1) & 7) << 4))) = f2bf(v1);
            *(unsigned short*)(base + (r64 + 2) * 512 + ((col * 2) ^ (((r64 + 2) & 7) << 4))) = f2bf(v2);
            *(unsigned short*)(base + (r64 + 3) * 512 + ((col * 2) ^ (((r64 + 3) & 7) << 4))) = f2bf(v3);
          }
        }
      }
    }
    // T14: prefetch x residual into registers; latency hides under attention
    if constexpr (!IS_COL) {
#pragma unroll
      for (int dt = 0; dt < 2; ++dt) {
        int c = h * 64 + dt * 32 + l31;
        const float* xb = x + (size_t)c * NPIX + pixbase + i0w;
#pragma unroll
        for (int q = 0; q < 4; ++q)
          xv[dt][q] = *(const float4*)(xb + q * 8 + hi * 4);
      }
    }
    __syncthreads();

    // ---------------- attention phase ----------------
    const int swz = (l31 & 7) << 4;
    bf16x8 qf[4];
    {
      const char* qrow = (const char*)Qt + (i0w + l31) * 128;
#pragma unroll
      for (int ks = 0; ks < 4; ++ks)
        qf[ks] = *(const bf16x8*)(qrow + ((ks * 32 + hi * 16) ^ swz));
    }

    f32x16 s[8] = {};
    __builtin_amdgcn_s_setprio(1);
#pragma unroll
    for (int jt = 0; jt < 8; ++jt) {
      const char* kr = (const char*)Kt + (jt * 32 + l31) * 128;
#pragma unroll
      for (int ks = 0; ks < 4; ++ks) {
        bf16x8 kf = *(const bf16x8*)(kr + ((ks * 32 + hi * 16) ^ swz));
        s[jt] = __builtin_amdgcn_mfma_f32_32x32x16_bf16(kf, qf[ks], s[jt], 0, 0, 0);
      }
    }
    __builtin_amdgcn_s_setprio(0);

    float mx = -3.4e38f;
#pragma unroll
    for (int jt = 0; jt < 8; ++jt)
#pragma unroll
      for (int r = 0; r < 16; ++r) mx = fmaxf(mx, s[jt][r]);
    mx = fmaxf(mx, __shfl_xor(mx, 32, 64));
    float sum = 0.f;
#pragma unroll
    for (int jt = 0; jt < 8; ++jt)
#pragma unroll
      for (int r = 0; r < 16; ++r) {
        float p = __expf(s[jt][r] - mx);
        s[jt][r] = p; sum += p;
      }
    sum += __shfl_xor(sum, 32, 64);
    float inv = 1.f / sum;

    bf16x8 pf[16];
#pragma unroll
    for (int jt = 0; jt < 8; ++jt)
#pragma unroll
      for (int kb = 0; kb < 2; ++kb) {
        int kt2 = jt * 2 + kb;
        unsigned pA0 = cvtpk(s[jt][kb * 8 + 0] * inv, s[jt][kb * 8 + 1] * inv);
        unsigned pA1 = cvtpk(s[jt][kb * 8 + 2] * inv, s[jt][kb * 8 + 3] * inv);
        unsigned pB0 = cvtpk(s[jt][kb * 8 + 4] * inv, s[jt][kb * 8 + 5] * inv);
        unsigned pB1 = cvtpk(s[jt][kb * 8 + 6] * inv, s[jt][kb * 8 + 7] * inv);
        unsigned s0 = hi ? pA0 : pB0;
        unsigned s1 = hi ? pA1 : pB1;
        unsigned r0 = (unsigned)__shfl_xor((int)s0, 32, 64);
        unsigned r1 = (unsigned)__shfl_xor((int)s1, 32, 64);
        union { unsigned u[4]; bf16x8 v; } pk_;
        pk_.u[0] = hi ? r0 : pA0;
        pk_.u[1] = hi ? r1 : pA1;
        pk_.u[2] = hi ? pB0 : r0;
        pk_.u[3] = hi ? pB1 : r1;
        pf[kt2] = pk_.v;
      }

    f32x16 o[2] = {};
    __builtin_amdgcn_s_setprio(1);
#pragma unroll
    for (int dt = 0; dt < 2; ++dt) {
      const char* vr = (const char*)Vn + (dt * 32 + l31) * 512;
#pragma unroll
      for (int kt2 = 0; kt2 < 16; ++kt2) {
        bf16x8 vf = *(const bf16x8*)(vr + ((kt2 * 32 + hi * 16) ^ swz));
        o[dt] = __builtin_amdgcn_mfma_f32_32x32x16_bf16(pf[kt2], vf, o[dt], 0, 0, 0);
      }
    }
    __builtin_amdgcn_s_setprio(0);

    // epilogue: lane(hi, d=dt*32+l31) holds O^T[i=q*8+hi*4+m][d], reg 4q+m
    if constexpr (!IS_COL) {
#pragma unroll
      for (int dt = 0; dt < 2; ++dt) {
        int c = h * 64 + dt * 32 + l31;
        unsigned short* ob = outnat + (size_t)c * NPIX + pixbase + i0w;
#pragma unroll
        for (int q = 0; q < 4; ++q) {
          int ib = q * 8 + hi * 4;
          float4 vv;
          vv.x = o[dt][q * 4 + 0] + xv[dt][q].x;
          vv.y = o[dt][q * 4 + 1] + xv[dt][q].y;
          vv.z = o[dt][q * 4 + 2] + xv[dt][q].z;
          vv.w = o[dt][q * 4 + 3] + xv[dt][q].w;
          ushort4 pk;
          pk.x = f2bf(vv.x); pk.y = f2bf(vv.y); pk.z = f2bf(vv.z); pk.w = f2bf(vv.w);
          *(ushort4*)(ob + ib) = pk;
          o[dt][q * 4 + 0] = vv.x; o[dt][q * 4 + 1] = vv.y;
          o[dt][q * 4 + 2] = vv.z; o[dt][q * 4 + 3] = vv.w;
        }
      }
      __syncthreads();                     // qkv reads done -> overlay Obt
      unsigned short* Obt = Qt;            // [256 i][72 d] (36.8K, over Qt/Kt)
#pragma unroll
      for (int dt = 0; dt < 2; ++dt) {
        int d = dt * 32 + l31;
#pragma unroll
        for (int q = 0; q < 4; ++q)
#pragma unroll
          for (int m = 0; m < 4; ++m)
            Obt[(i0w + q * 8 + hi * 4 + m) * 72 + d] = f2bf(o[dt][q * 4 + m]);
      }
      __syncthreads();
      int row = tid >> 1, half = tid & 1;
      const unsigned short* src = Obt + row * 72 + half * 32;
      unsigned short* dst = outbt + ((size_t)row * 256 + fix) * 512 + h * 64 + half * 32;
#pragma unroll
      for (int c4 = 0; c4 < 4; ++c4)
        *(uint4*)(dst + c4 * 8) = *(const uint4*)(src + c4 * 8);
    } else {
#pragma unroll
      for (int dt = 0; dt < 2; ++dt) {
        int c = h * 64 + dt * 32 + l31;
        unsigned short* ob = outnat + (size_t)c * NPIX + pixbase + i0w;
#pragma unroll
        for (int q = 0; q < 4; ++q) {
          ushort4 pkv;
          pkv.x = f2bf(o[dt][q * 4 + 0]);
          pkv.y = f2bf(o[dt][q * 4 + 1]);
          pkv.z = f2bf(o[dt][q * 4 + 2]);
          pkv.w = f2bf(o[dt][q * 4 + 3]);
          *(ushort4*)(ob + q * 8 + hi * 4) = pkv;
        }
      }
      __syncthreads();                     // all qkv reads done before next head
    }
  }
}

// --------- final: out[c][s][l] = bf2f(out1nat) + colout_bt[c][l][s] ---------
__global__ __launch_bounds__(256) void k_final(const unsigned short* __restrict__ colt,
                                               const unsigned short* __restrict__ out1nat,
                                               float* __restrict__ out) {
  __shared__ unsigned short Xs[64 * 68];
  int c = blockIdx.y;
  int lt = blockIdx.x & 3, st = blockIdx.x >> 2;
  int l0 = lt * 64, s0 = st * 64;
  int t = threadIdx.x;
  for (int rep = 0; rep < 4; ++rep) {
    int f = rep * 256 + t, li = f >> 4, jj = f & 15;
    ushort4 v = *(const ushort4*)(colt + (size_t)c * NPIX + (size_t)(l0 + li) * 256 + s0 + jj * 4);
    *(ushort4*)(Xs + li * 68 + jj * 4) = v;
  }
  __syncthreads();
  int si = t >> 2, q = t & 3;
  size_t rowoff = (size_t)c * NPIX + (size_t)(s0 + si) * 256 + l0 + q * 16;
  float* drow = out + rowoff;
  for (int h4 = 0; h4 < 4; ++h4) {
    ushort4 nv = *(const ushort4*)(out1nat + rowoff + h4 * 4);
    float4 a;
    a.x = bf2f(nv.x) + bf2f(Xs[(q * 16 + h4 * 4 + 0) * 68 + si]);
    a.y = bf2f(nv.y) + bf2f(Xs[(q * 16 + h4 * 4 + 1) * 68 + si]);
    a.z = bf2f(nv.z) + bf2f(Xs[(q * 16 + h4 * 4 + 2) * 68 + si]);
    a.w = bf2f(nv.w) + bf2f(Xs[(q * 16 + h4 * 4 + 3) * 68 + si]);
    *(float4*)(drow + h4 * 4) = a;
  }
}

extern "C" void kernel_launch(void* const* d_in, const int* in_sizes, int n_in,
                              void* d_out, int out_size, void* d_ws, size_t ws_size,
                              hipStream_t stream) {
  const float* x  = (const float*)d_in[0];
  const float* Wr = (const float*)d_in[1];
  const float* br = (const float*)d_in[2];
  const float* Wc = (const float*)d_in[3];
  const float* bc = (const float*)d_in[4];
  float* out = (float*)d_out;
  char* ws = (char*)d_ws;
  unsigned short* xT     = (unsigned short*)(ws);                        // 64 MB [p][c]
  unsigned short* o1bt   = (unsigned short*)(ws + 67108864);             // 64 MB [l*256+s][c]
  unsigned short* colout = (unsigned short*)(ws + 134217728);            // 64 MB [c][l*256+s]
  unsigned short* o1nat  = (unsigned short*)(ws + 201326592);            // 64 MB [c][s*256+l]
  unsigned short* Wrb    = (unsigned short*)(ws + 268435456);            // 1.5 MB
  unsigned short* Wcb    = (unsigned short*)(ws + 270008320);            // 1.5 MB

  k_cvt<<<768, 256, 0, stream>>>(Wr, Wrb, 196608);
  k_cvt<<<768, 256, 0, stream>>>(Wc, Wcb, 196608);
  k_cvt_transpose<<<dim3(1024, 8), 256, 0, stream>>>(x, xT);
  // row side: fix = s, queries i = l; out1 = x + rowO
  k_fused<0><<<dim3(8, 128), 512, 0, stream>>>(xT, Wrb, br, x, o1nat, o1bt);
  // col side: fix = l, queries i = s; panel = out1^T (pixel order l*256+s)
  k_fused<1><<<dim3(8, 128), 512, 0, stream>>>(o1bt, Wcb, bc, nullptr, colout, nullptr);
  k_final<<<dim3(16, 512), 256, 0, stream>>>(colout, o1nat, out);
}

// Round 13
// 501.647 us; speedup vs baseline: 1.9791x; 1.9791x over previous
//
#include <hip/hip_runtime.h>

typedef __bf16 bf16_t;
typedef __attribute__((ext_vector_type(8))) __bf16 bf16x8;
typedef __attribute__((ext_vector_type(4))) float f32x4;
typedef __attribute__((ext_vector_type(16))) float f32x16;

#define NH   8
#define DH   64
#define DD   512
#define NPIX 65536   // 256*256

__device__ __forceinline__ unsigned short f2bf(float f) {
  unsigned int u = __builtin_bit_cast(unsigned int, f);
  u += 0x7fffu + ((u >> 16) & 1u);
  return (unsigned short)(u >> 16);
}
__device__ __forceinline__ float bf2f(unsigned short b) {
  return __builtin_bit_cast(float, ((unsigned int)b) << 16);
}
__device__ __forceinline__ unsigned cvtpk(float a, float b) {
  unsigned r;
  asm("v_cvt_pk_bf16_f32 %0, %1, %2" : "=v"(r) : "v"(a), "v"(b));
  return r;
}

__device__ __forceinline__ void gload_lds16(const void* g, void* l) {
  __builtin_amdgcn_global_load_lds(
      (const __attribute__((address_space(1))) void*)(uintptr_t)g,
      (__attribute__((address_space(3))) void*)(uintptr_t)l, 16, 0, 0);
}

// -------- fp32 -> bf16 convert, both weight matrices in one launch ----------
__global__ __launch_bounds__(256) void k_cvt2(const float* __restrict__ inA,
                                              const float* __restrict__ inB,
                                              unsigned short* __restrict__ outA,
                                              unsigned short* __restrict__ outB,
                                              int n4) {
  int i = blockIdx.x * 256 + threadIdx.x;
  const float* in; unsigned short* out; int j;
  if (i < n4) { in = inA; out = outA; j = i; }
  else if (i < 2 * n4) { in = inB; out = outB; j = i - n4; }
  else return;
  float4 v = ((const float4*)in)[j];
  ushort4 o; o.x = f2bf(v.x); o.y = f2bf(v.y); o.z = f2bf(v.z); o.w = f2bf(v.w);
  ((ushort4*)out)[j] = o;
}

// ------------- x [512][65536] f32 -> x^T [65536][512] bf16 ------------------
__global__ __launch_bounds__(256) void k_cvt_transpose(const float* __restrict__ x,
                                                       unsigned short* __restrict__ xt) {
  __shared__ unsigned short Xs[64 * 68];
  int p0 = blockIdx.x * 64, c0 = blockIdx.y * 64;
  int t = threadIdx.x;
  for (int rep = 0; rep < 4; ++rep) {
    int f = rep * 256 + t, i = f >> 4, jj = f & 15;
    float4 v = *(const float4*)(x + (size_t)(c0 + i) * NPIX + p0 + jj * 4);
    ushort4 o; o.x = f2bf(v.x); o.y = f2bf(v.y); o.z = f2bf(v.z); o.w = f2bf(v.w);
    *(ushort4*)(Xs + i * 68 + jj * 4) = o;
  }
  __syncthreads();
  int j = t >> 2, q = t & 3;
  unsigned short* dst = xt + (size_t)(p0 + j) * DD + c0 + q * 16;
  for (int h2 = 0; h2 < 2; ++h2) {
    union { unsigned short u[8]; uint4 v; } pk;
    for (int cc = 0; cc < 8; ++cc) pk.u[cc] = Xs[(q * 16 + h2 * 8 + cc) * 68 + j];
    *(uint4*)(dst + h2 * 8) = pk.v;
  }
}

// -------- FUSED QKV-projection + axial attention, one block per (h,fix) -----
// (R11 structure, verbatim — HW-proven at 505 us total.)
// GEMM phase: C[192][256] = W_h[192x512] @ panel[fix*256..+256, 512]^T + bias.
//   8 waves (2m x 4n), wave tile 96x64, mfma_32x32x16, double-buffered LDS
//   staging (2 x 56 KiB). W rows gathered: global row (r>>6)*512 + h*64 + (r&63).
// Epilogue: q,k stored TRANSPOSED ([p][c], XOR-swizzled), v natural ([d][j],
//   XOR-swizzled) into LDS (96 KiB, overlays staging after final barrier).
// Attention phase: QK^T -> in-lane softmax -> in-register cvt_pk/shfl
//   P-regroup -> PV, reading K/V/Q from the LDS qkv.
// NOTE (R12 lesson): nothing extra may live across the attention phase —
//   s[8] (128 f32) + acc put the unified register file at its edge; any added
//   cross-phase live state (e.g. prefetched x residual) spills ~600 MB scratch.
template <int IS_COL>
__global__ __launch_bounds__(512, 2) void k_fused(const unsigned short* __restrict__ panel,
                                                  const unsigned short* __restrict__ Wb,
                                                  const float* __restrict__ bias,
                                                  const float* __restrict__ x,
                                                  unsigned short* __restrict__ outnat,
                                                  unsigned short* __restrict__ outbt) {
  __shared__ unsigned short smem[57344];   // 112 KiB
  const int tid = threadIdx.x, lane = tid & 63, wave = tid >> 6;
  const int l31 = lane & 31, hi = lane >> 5;
  // chunked-XCD remap: the 8 h-siblings of one fix share a B-panel and land
  // on one XCD (lid = fix*8 + h).
  int bid = blockIdx.y * 8 + blockIdx.x;
  int lid = (bid & 7) * 256 + (bid >> 3);
  const int h = lid & 7, fix = lid >> 3;
  const size_t pixbase = (size_t)fix * 256;
  const int wm = wave >> 2, wn = wave & 3;   // 2 x 4 wave grid
  const int i0w = wave * 32;

  const unsigned short* Pbase = panel + pixbase * 512;

  // stage K-tile kt into buf b: A = W_h [192][64], B = panel [256][64].
  // T2: source chunk pre-swizzled so ds_reads XOR ((row&7)<<4) conflict-free.
  auto STAGE = [&](int b, int kt) {
    unsigned short* Ab = smem + b * 28672;
    unsigned short* Bb = Ab + 12288;
#pragma unroll
    for (int it = 0; it < 3; ++it) {       // A: 192 rows x 8 chunks
      int f = it * 512 + tid;
      int row = f >> 3;
      int cc = (f & 7) ^ (row & 7);
      int grow = (row >> 6) * 512 + h * 64 + (row & 63);
      gload_lds16(Wb + (size_t)grow * 512 + kt * 64 + cc * 8, Ab + f * 8);
    }
#pragma unroll
    for (int it = 0; it < 4; ++it) {       // B: 256 rows x 8 chunks
      int f = it * 512 + tid;
      int row = f >> 3;
      int cc = (f & 7) ^ (row & 7);
      gload_lds16(Pbase + (size_t)row * 512 + kt * 64 + cc * 8, Bb + f * 8);
    }
  };

  f32x16 acc[3][2] = {};
  STAGE(0, 0);
  asm volatile("s_waitcnt vmcnt(0)" ::: "memory");
  __syncthreads();
  int cur = 0;
  for (int kt = 0; kt < 8; ++kt) {
    if (kt < 7) STAGE(cur ^ 1, kt + 1);    // prefetch next tile
    const char* Ad = (const char*)smem + cur * 57344;
    const char* Bd = Ad + 24576;
#pragma unroll
    for (int ks = 0; ks < 4; ++ks) {
      bf16x8 afr[3], bfr[2];
#pragma unroll
      for (int mt = 0; mt < 3; ++mt) {
        int r = wm * 96 + mt * 32 + l31;
        afr[mt] = *(const bf16x8*)(Ad + r * 128 + ((ks * 32 + hi * 16) ^ ((r & 7) << 4)));
      }
#pragma unroll
      for (int nt = 0; nt < 2; ++nt) {
        int r = wn * 64 + nt * 32 + l31;
        bfr[nt] = *(const bf16x8*)(Bd + r * 128 + ((ks * 32 + hi * 16) ^ ((r & 7) << 4)));
      }
      __builtin_amdgcn_s_setprio(1);
#pragma unroll
      for (int mt = 0; mt < 3; ++mt)
#pragma unroll
        for (int nt = 0; nt < 2; ++nt)
          acc[mt][nt] = __builtin_amdgcn_mfma_f32_32x32x16_bf16(afr[mt], bfr[nt], acc[mt][nt], 0, 0, 0);
      __builtin_amdgcn_s_setprio(0);
    }
    asm volatile("s_waitcnt vmcnt(0)" ::: "memory");
    __syncthreads();
    cur ^= 1;
  }
  // all LDS reads of staging done (loop-end barrier) -> overlay qkv
  unsigned short* Qt = smem;               // [256 p][64 c] swz, 32 KiB
  unsigned short* Kt = smem + 16384;       // [256 j][64 c] swz, 32 KiB
  unsigned short* Vn = smem + 32768;       // [64 d][256 j] swz, 32 KiB
  // C row = wm*96 + mt*32 + 8q + 4hi + j (j<4), col = wn*64 + nt*32 + l31
#pragma unroll
  for (int mt = 0; mt < 3; ++mt) {
    int rb = wm * 96 + mt * 32 + 4 * hi;
#pragma unroll
    for (int q = 0; q < 4; ++q) {
      int crow = rb + 8 * q;               // strip of 4 rows
      int sel = crow >> 6, r64 = crow & 63;
      f32x4 bv = *(const f32x4*)(bias + sel * 512 + h * 64 + r64);
#pragma unroll
      for (int nt = 0; nt < 2; ++nt) {
        int col = wn * 64 + nt * 32 + l31;
        float v0 = acc[mt][nt][q * 4 + 0] + bv.x;
        float v1 = acc[mt][nt][q * 4 + 1] + bv.y;
        float v2 = acc[mt][nt][q * 4 + 2] + bv.z;
        float v3 = acc[mt][nt][q * 4 + 3] + bv.w;
        if (sel < 2) {                     // q,k -> transposed [p][c]
          ushort4 pk;
          pk.x = f2bf(v0); pk.y = f2bf(v1); pk.z = f2bf(v2); pk.w = f2bf(v3);
          char* base = (char*)(sel ? Kt : Qt);
          *(ushort4*)(base + col * 128 + ((r64 * 2) ^ ((col & 7) << 4))) = pk;
        } else {                           // v -> natural [d][j]
          char* base = (char*)Vn;
          *(unsigned short*)(base + (r64 + 0) * 512 + ((col * 2) ^ (((r64 + 0) & 7) << 4))) = f2bf(v0);
          *(unsigned short*)(base + (r64 + 1) * 512 + ((col * 2) ^ (((r64 + 1) & 7) << 4))) = f2bf(v1);
          *(unsigned short*)(base + (r64 + 2) * 512 + ((col * 2) ^ (((r64 + 2) & 7) << 4))) = f2bf(v2);
          *(unsigned short*)(base + (r64 + 3) * 512 + ((col * 2) ^ (((r64 + 3) & 7) << 4))) = f2bf(v3);
        }
      }
    }
  }
  __syncthreads();

  // ---------------- attention phase ----------------
  const int swz = (l31 & 7) << 4;
  bf16x8 qf[4];
  {
    const char* qrow = (const char*)Qt + (i0w + l31) * 128;
#pragma unroll
    for (int ks = 0; ks < 4; ++ks)
      qf[ks] = *(const bf16x8*)(qrow + ((ks * 32 + hi * 16) ^ swz));
  }

  // QK^T: S^T[j][i], j over 8 jt tiles, i = l31 (+ wave's 32-query window)
  f32x16 s[8] = {};
  __builtin_amdgcn_s_setprio(1);
#pragma unroll
  for (int jt = 0; jt < 8; ++jt) {
    const char* kr = (const char*)Kt + (jt * 32 + l31) * 128;
#pragma unroll
    for (int ks = 0; ks < 4; ++ks) {
      bf16x8 kf = *(const bf16x8*)(kr + ((ks * 32 + hi * 16) ^ swz));
      s[jt] = __builtin_amdgcn_mfma_f32_32x32x16_bf16(kf, qf[ks], s[jt], 0, 0, 0);
    }
  }
  __builtin_amdgcn_s_setprio(0);

  // softmax over j (128 in-lane values; partner half has the other 128)
  float mx = -3.4e38f;
#pragma unroll
  for (int jt = 0; jt < 8; ++jt)
#pragma unroll
    for (int r = 0; r < 16; ++r) mx = fmaxf(mx, s[jt][r]);
  mx = fmaxf(mx, __shfl_xor(mx, 32, 64));
  float sum = 0.f;
#pragma unroll
  for (int jt = 0; jt < 8; ++jt)
#pragma unroll
    for (int r = 0; r < 16; ++r) {
      float p = __expf(s[jt][r] - mx);
      s[jt][r] = p; sum += p;
    }
  sum += __shfl_xor(sum, 32, 64);
  float inv = 1.f / sum;

  // P fragments (A-operand for PV), normalized, in-register regroup
  bf16x8 pf[16];
#pragma unroll
  for (int jt = 0; jt < 8; ++jt)
#pragma unroll
    for (int kb = 0; kb < 2; ++kb) {
      int kt2 = jt * 2 + kb;
      unsigned pA0 = cvtpk(s[jt][kb * 8 + 0] * inv, s[jt][kb * 8 + 1] * inv);
      unsigned pA1 = cvtpk(s[jt][kb * 8 + 2] * inv, s[jt][kb * 8 + 3] * inv);
      unsigned pB0 = cvtpk(s[jt][kb * 8 + 4] * inv, s[jt][kb * 8 + 5] * inv);
      unsigned pB1 = cvtpk(s[jt][kb * 8 + 6] * inv, s[jt][kb * 8 + 7] * inv);
      unsigned s0 = hi ? pA0 : pB0;
      unsigned s1 = hi ? pA1 : pB1;
      unsigned r0 = (unsigned)__shfl_xor((int)s0, 32, 64);
      unsigned r1 = (unsigned)__shfl_xor((int)s1, 32, 64);
      union { unsigned u[4]; bf16x8 v; } pk_;
      pk_.u[0] = hi ? r0 : pA0;
      pk_.u[1] = hi ? r1 : pA1;
      pk_.u[2] = hi ? pB0 : r0;
      pk_.u[3] = hi ? pB1 : r1;
      pf[kt2] = pk_.v;
    }

  // PV: O^T[i][d]
  f32x16 o[2] = {};
  __builtin_amdgcn_s_setprio(1);
#pragma unroll
  for (int dt = 0; dt < 2; ++dt) {
    const char* vr = (const char*)Vn + (dt * 32 + l31) * 512;
#pragma unroll
    for (int kt2 = 0; kt2 < 16; ++kt2) {
      bf16x8 vf = *(const bf16x8*)(vr + ((kt2 * 32 + hi * 16) ^ swz));
      o[dt] = __builtin_amdgcn_mfma_f32_32x32x16_bf16(pf[kt2], vf, o[dt], 0, 0, 0);
    }
  }
  __builtin_amdgcn_s_setprio(0);

  // epilogue: lane(hi, d=dt*32+l31) holds O^T[i = q*8 + hi*4 + m][d], reg 4q+m
  if (!IS_COL) {
#pragma unroll
    for (int dt = 0; dt < 2; ++dt) {
      int c = h * 64 + dt * 32 + l31;
      const float* xb = x + (size_t)c * NPIX + pixbase + i0w;
      unsigned short* ob = outnat + (size_t)c * NPIX + pixbase + i0w;
#pragma unroll
      for (int q = 0; q < 4; ++q) {
        int ib = q * 8 + hi * 4;
        float4 xv = *(const float4*)(xb + ib);
        float4 vv;
        vv.x = o[dt][q * 4 + 0] + xv.x;
        vv.y = o[dt][q * 4 + 1] + xv.y;
        vv.z = o[dt][q * 4 + 2] + xv.z;
        vv.w = o[dt][q * 4 + 3] + xv.w;
        ushort4 pk;
        pk.x = f2bf(vv.x); pk.y = f2bf(vv.y); pk.z = f2bf(vv.z); pk.w = f2bf(vv.w);
        *(ushort4*)(ob + ib) = pk;
        o[dt][q * 4 + 0] = vv.x; o[dt][q * 4 + 1] = vv.y;
        o[dt][q * 4 + 2] = vv.z; o[dt][q * 4 + 3] = vv.w;
      }
    }
    __syncthreads();                       // qkv reads done -> overlay Obt
    unsigned short* Obt = smem;            // [256 i][72 d]
#pragma unroll
    for (int dt = 0; dt < 2; ++dt) {
      int d = dt * 32 + l31;
#pragma unroll
      for (int q = 0; q < 4; ++q)
#pragma unroll
        for (int m = 0; m < 4; ++m)
          Obt[(i0w + q * 8 + hi * 4 + m) * 72 + d] = f2bf(o[dt][q * 4 + m]);
    }
    __syncthreads();
    int row = tid >> 1, half = tid & 1;
    const unsigned short* src = Obt + row * 72 + half * 32;
    unsigned short* dst = outbt + ((size_t)row * 256 + fix) * 512 + h * 64 + half * 32;
#pragma unroll
    for (int c4 = 0; c4 < 4; ++c4)
      *(uint4*)(dst + c4 * 8) = *(const uint4*)(src + c4 * 8);
  } else {
#pragma unroll
    for (int dt = 0; dt < 2; ++dt) {
      int c = h * 64 + dt * 32 + l31;
      unsigned short* ob = outnat + (size_t)c * NPIX + pixbase + i0w;
#pragma unroll
      for (int q = 0; q < 4; ++q) {
        ushort4 pkv;
        pkv.x = f2bf(o[dt][q * 4 + 0]);
        pkv.y = f2bf(o[dt][q * 4 + 1]);
        pkv.z = f2bf(o[dt][q * 4 + 2]);
        pkv.w = f2bf(o[dt][q * 4 + 3]);
        *(ushort4*)(ob + q * 8 + hi * 4) = pkv;
      }
    }
  }
}

// --------- final: out[c][s][l] = bf2f(out1nat) + colout_bt[c][l][s] ---------
__global__ __launch_bounds__(256) void k_final(const unsigned short* __restrict__ colt,
                                               const unsigned short* __restrict__ out1nat,
                                               float* __restrict__ out) {
  __shared__ unsigned short Xs[64 * 68];
  int c = blockIdx.y;
  int lt = blockIdx.x & 3, st = blockIdx.x >> 2;
  int l0 = lt * 64, s0 = st * 64;
  int t = threadIdx.x;
  for (int rep = 0; rep < 4; ++rep) {
    int f = rep * 256 + t, li = f >> 4, jj = f & 15;
    ushort4 v = *(const ushort4*)(colt + (size_t)c * NPIX + (size_t)(l0 + li) * 256 + s0 + jj * 4);
    *(ushort4*)(Xs + li * 68 + jj * 4) = v;
  }
  __syncthreads();
  int si = t >> 2, q = t & 3;
  size_t rowoff = (size_t)c * NPIX + (size_t)(s0 + si) * 256 + l0 + q * 16;
  float* drow = out + rowoff;
  for (int h4 = 0; h4 < 4; ++h4) {
    ushort4 nv = *(const ushort4*)(out1nat + rowoff + h4 * 4);
    float4 a;
    a.x = bf2f(nv.x) + bf2f(Xs[(q * 16 + h4 * 4 + 0) * 68 + si]);
    a.y = bf2f(nv.y) + bf2f(Xs[(q * 16 + h4 * 4 + 1) * 68 + si]);
    a.z = bf2f(nv.z) + bf2f(Xs[(q * 16 + h4 * 4 + 2) * 68 + si]);
    a.w = bf2f(nv.w) + bf2f(Xs[(q * 16 + h4 * 4 + 3) * 68 + si]);
    *(float4*)(drow + h4 * 4) = a;
  }
}

extern "C" void kernel_launch(void* const* d_in, const int* in_sizes, int n_in,
                              void* d_out, int out_size, void* d_ws, size_t ws_size,
                              hipStream_t stream) {
  const float* x  = (const float*)d_in[0];
  const float* Wr = (const float*)d_in[1];
  const float* br = (const float*)d_in[2];
  const float* Wc = (const float*)d_in[3];
  const float* bc = (const float*)d_in[4];
  float* out = (float*)d_out;
  char* ws = (char*)d_ws;
  unsigned short* xT     = (unsigned short*)(ws);                        // 64 MB [p][c]
  unsigned short* o1bt   = (unsigned short*)(ws + 67108864);             // 64 MB [l*256+s][c]
  unsigned short* colout = (unsigned short*)(ws + 134217728);            // 64 MB [c][l*256+s]
  unsigned short* o1nat  = (unsigned short*)(ws + 201326592);            // 64 MB [c][s*256+l]
  unsigned short* Wrb    = (unsigned short*)(ws + 268435456);            // 1.5 MB
  unsigned short* Wcb    = (unsigned short*)(ws + 270008320);            // 1.5 MB

  k_cvt2<<<1536, 256, 0, stream>>>(Wr, Wc, Wrb, Wcb, 196608);
  k_cvt_transpose<<<dim3(1024, 8), 256, 0, stream>>>(x, xT);
  // row side: fix = s, queries i = l; out1 = x + rowO
  k_fused<0><<<dim3(8, 256), 512, 0, stream>>>(xT, Wrb, br, x, o1nat, o1bt);
  // col side: fix = l, queries i = s; panel = out1^T (pixel order l*256+s)
  k_fused<1><<<dim3(8, 256), 512, 0, stream>>>(o1bt, Wcb, bc, nullptr, colout, nullptr);
  k_final<<<dim3(16, 512), 256, 0, stream>>>(colout, o1nat, out);
}

// Round 14
// 482.886 us; speedup vs baseline: 2.0560x; 1.0389x over previous
//
#include <hip/hip_runtime.h>

typedef __bf16 bf16_t;
typedef __attribute__((ext_vector_type(8))) __bf16 bf16x8;
typedef __attribute__((ext_vector_type(4))) float f32x4;
typedef __attribute__((ext_vector_type(16))) float f32x16;

#define NH   8
#define DH   64
#define DD   512
#define NPIX 65536   // 256*256

__device__ __forceinline__ unsigned short f2bf(float f) {
  unsigned int u = __builtin_bit_cast(unsigned int, f);
  u += 0x7fffu + ((u >> 16) & 1u);
  return (unsigned short)(u >> 16);
}
__device__ __forceinline__ float bf2f(unsigned short b) {
  return __builtin_bit_cast(float, ((unsigned int)b) << 16);
}
__device__ __forceinline__ unsigned cvtpk(float a, float b) {
  unsigned r;
  asm("v_cvt_pk_bf16_f32 %0, %1, %2" : "=v"(r) : "v"(a), "v"(b));
  return r;
}

__device__ __forceinline__ void gload_lds16(const void* g, void* l) {
  __builtin_amdgcn_global_load_lds(
      (const __attribute__((address_space(1))) void*)(uintptr_t)g,
      (__attribute__((address_space(3))) void*)(uintptr_t)l, 16, 0, 0);
}

// -------- fp32 -> bf16 convert, both weight matrices in one launch ----------
__global__ __launch_bounds__(256) void k_cvt2(const float* __restrict__ inA,
                                              const float* __restrict__ inB,
                                              unsigned short* __restrict__ outA,
                                              unsigned short* __restrict__ outB,
                                              int n4) {
  int i = blockIdx.x * 256 + threadIdx.x;
  const float* in; unsigned short* out; int j;
  if (i < n4) { in = inA; out = outA; j = i; }
  else if (i < 2 * n4) { in = inB; out = outB; j = i - n4; }
  else return;
  float4 v = ((const float4*)in)[j];
  ushort4 o; o.x = f2bf(v.x); o.y = f2bf(v.y); o.z = f2bf(v.z); o.w = f2bf(v.w);
  ((ushort4*)out)[j] = o;
}

// ------------- x [512][65536] f32 -> x^T [65536][512] bf16 ------------------
__global__ __launch_bounds__(256) void k_cvt_transpose(const float* __restrict__ x,
                                                       unsigned short* __restrict__ xt) {
  __shared__ unsigned short Xs[64 * 68];
  int p0 = blockIdx.x * 64, c0 = blockIdx.y * 64;
  int t = threadIdx.x;
  for (int rep = 0; rep < 4; ++rep) {
    int f = rep * 256 + t, i = f >> 4, jj = f & 15;
    float4 v = *(const float4*)(x + (size_t)(c0 + i) * NPIX + p0 + jj * 4);
    ushort4 o; o.x = f2bf(v.x); o.y = f2bf(v.y); o.z = f2bf(v.z); o.w = f2bf(v.w);
    *(ushort4*)(Xs + i * 68 + jj * 4) = o;
  }
  __syncthreads();
  int j = t >> 2, q = t & 3;
  unsigned short* dst = xt + (size_t)(p0 + j) * DD + c0 + q * 16;
  for (int h2 = 0; h2 < 2; ++h2) {
    union { unsigned short u[8]; uint4 v; } pk;
    for (int cc = 0; cc < 8; ++cc) pk.u[cc] = Xs[(q * 16 + h2 * 8 + cc) * 68 + j];
    *(uint4*)(dst + h2 * 8) = pk.v;
  }
}

// -------- FUSED QKV-projection + axial attention, one block per (h,fix) -----
// (R11/R13 structure; R14 change: the residual for IS_COL=0 is read from an
//  LDS-staged bf16 tile of xT (32 KiB at byte 112K, loaded via 4 extra
//  global_load_lds that drain under the existing first vmcnt(0)) instead of
//  128 MB of fp32 x reads in the epilogue.)
// NOTE (R12 lesson): nothing extra may live in registers across the attention
//  phase — s[8] + acc put the unified register file at its edge.
template <int IS_COL>
__global__ __launch_bounds__(512, 2) void k_fused(const unsigned short* __restrict__ panel,
                                                  const unsigned short* __restrict__ Wb,
                                                  const float* __restrict__ bias,
                                                  unsigned short* __restrict__ outnat,
                                                  unsigned short* __restrict__ outbt) {
  __shared__ unsigned short smem[IS_COL ? 57344 : 73728];  // 112 / 144 KiB
  const int tid = threadIdx.x, lane = tid & 63, wave = tid >> 6;
  const int l31 = lane & 31, hi = lane >> 5;
  // chunked-XCD remap: the 8 h-siblings of one fix share a B-panel and land
  // on one XCD (lid = fix*8 + h).
  int bid = blockIdx.y * 8 + blockIdx.x;
  int lid = (bid & 7) * 256 + (bid >> 3);
  const int h = lid & 7, fix = lid >> 3;
  const size_t pixbase = (size_t)fix * 256;
  const int wm = wave >> 2, wn = wave & 3;   // 2 x 4 wave grid
  const int i0w = wave * 32;

  const unsigned short* Pbase = panel + pixbase * 512;

  // stage K-tile kt into buf b: A = W_h [192][64], B = panel [256][64].
  // T2: source chunk pre-swizzled so ds_reads XOR ((row&7)<<4) conflict-free.
  auto STAGE = [&](int b, int kt) {
    unsigned short* Ab = smem + b * 28672;
    unsigned short* Bb = Ab + 12288;
#pragma unroll
    for (int it = 0; it < 3; ++it) {       // A: 192 rows x 8 chunks
      int f = it * 512 + tid;
      int row = f >> 3;
      int cc = (f & 7) ^ (row & 7);
      int grow = (row >> 6) * 512 + h * 64 + (row & 63);
      gload_lds16(Wb + (size_t)grow * 512 + kt * 64 + cc * 8, Ab + f * 8);
    }
#pragma unroll
    for (int it = 0; it < 4; ++it) {       // B: 256 rows x 8 chunks
      int f = it * 512 + tid;
      int row = f >> 3;
      int cc = (f & 7) ^ (row & 7);
      gload_lds16(Pbase + (size_t)row * 512 + kt * 64 + cc * 8, Bb + f * 8);
    }
  };

  // R14: stage the residual tile x^T[pixbase..+256][h*64..+64] -> LDS
  // [256 rows][64 ch] linear bf16 at byte 112K. Drains under first vmcnt(0).
  if constexpr (!IS_COL) {
    unsigned short* Xr = smem + 57344;     // byte 114688
#pragma unroll
    for (int it = 0; it < 4; ++it) {
      int f = it * 512 + tid;
      int row = f >> 3, ch = f & 7;
      gload_lds16(panel + (pixbase + row) * 512 + h * 64 + ch * 8, Xr + f * 8);
    }
  }

  f32x16 acc[3][2] = {};
  STAGE(0, 0);
  asm volatile("s_waitcnt vmcnt(0)" ::: "memory");
  __syncthreads();
  int cur = 0;
  for (int kt = 0; kt < 8; ++kt) {
    if (kt < 7) STAGE(cur ^ 1, kt + 1);    // prefetch next tile
    const char* Ad = (const char*)smem + cur * 57344;
    const char* Bd = Ad + 24576;
#pragma unroll
    for (int ks = 0; ks < 4; ++ks) {
      bf16x8 afr[3], bfr[2];
#pragma unroll
      for (int mt = 0; mt < 3; ++mt) {
        int r = wm * 96 + mt * 32 + l31;
        afr[mt] = *(const bf16x8*)(Ad + r * 128 + ((ks * 32 + hi * 16) ^ ((r & 7) << 4)));
      }
#pragma unroll
      for (int nt = 0; nt < 2; ++nt) {
        int r = wn * 64 + nt * 32 + l31;
        bfr[nt] = *(const bf16x8*)(Bd + r * 128 + ((ks * 32 + hi * 16) ^ ((r & 7) << 4)));
      }
      __builtin_amdgcn_s_setprio(1);
#pragma unroll
      for (int mt = 0; mt < 3; ++mt)
#pragma unroll
        for (int nt = 0; nt < 2; ++nt)
          acc[mt][nt] = __builtin_amdgcn_mfma_f32_32x32x16_bf16(afr[mt], bfr[nt], acc[mt][nt], 0, 0, 0);
      __builtin_amdgcn_s_setprio(0);
    }
    asm volatile("s_waitcnt vmcnt(0)" ::: "memory");
    __syncthreads();
    cur ^= 1;
  }
  // all LDS reads of staging done (loop-end barrier) -> overlay qkv
  unsigned short* Qt = smem;               // [256 p][64 c] swz, 32 KiB
  unsigned short* Kt = smem + 16384;       // [256 j][64 c] swz, 32 KiB
  unsigned short* Vn = smem + 32768;       // [64 d][256 j] swz, 32 KiB
  // C row = wm*96 + mt*32 + 8q + 4hi + j (j<4), col = wn*64 + nt*32 + l31
#pragma unroll
  for (int mt = 0; mt < 3; ++mt) {
    int rb = wm * 96 + mt * 32 + 4 * hi;
#pragma unroll
    for (int q = 0; q < 4; ++q) {
      int crow = rb + 8 * q;               // strip of 4 rows
      int sel = crow >> 6, r64 = crow & 63;
      f32x4 bv = *(const f32x4*)(bias + sel * 512 + h * 64 + r64);
#pragma unroll
      for (int nt = 0; nt < 2; ++nt) {
        int col = wn * 64 + nt * 32 + l31;
        float v0 = acc[mt][nt][q * 4 + 0] + bv.x;
        float v1 = acc[mt][nt][q * 4 + 1] + bv.y;
        float v2 = acc[mt][nt][q * 4 + 2] + bv.z;
        float v3 = acc[mt][nt][q * 4 + 3] + bv.w;
        if (sel < 2) {                     // q,k -> transposed [p][c]
          ushort4 pk;
          pk.x = f2bf(v0); pk.y = f2bf(v1); pk.z = f2bf(v2); pk.w = f2bf(v3);
          char* base = (char*)(sel ? Kt : Qt);
          *(ushort4*)(base + col * 128 + ((r64 * 2) ^ ((col & 7) << 4))) = pk;
        } else {                           // v -> natural [d][j]
          char* base = (char*)Vn;
          *(unsigned short*)(base + (r64 + 0) * 512 + ((col * 2) ^ (((r64 + 0) & 7) << 4))) = f2bf(v0);
          *(unsigned short*)(base + (r64 + 1) * 512 + ((col * 2) ^ (((r64 + 1) & 7) << 4))) = f2bf(v1);
          *(unsigned short*)(base + (r64 + 2) * 512 + ((col * 2) ^ (((r64 + 2) & 7) << 4))) = f2bf(v2);
          *(unsigned short*)(base + (r64 + 3) * 512 + ((col * 2) ^ (((r64 + 3) & 7) << 4))) = f2bf(v3);
        }
      }
    }
  }
  __syncthreads();

  // ---------------- attention phase ----------------
  const int swz = (l31 & 7) << 4;
  bf16x8 qf[4];
  {
    const char* qrow = (const char*)Qt + (i0w + l31) * 128;
#pragma unroll
    for (int ks = 0; ks < 4; ++ks)
      qf[ks] = *(const bf16x8*)(qrow + ((ks * 32 + hi * 16) ^ swz));
  }

  // QK^T: S^T[j][i], j over 8 jt tiles, i = l31 (+ wave's 32-query window)
  f32x16 s[8] = {};
  __builtin_amdgcn_s_setprio(1);
#pragma unroll
  for (int jt = 0; jt < 8; ++jt) {
    const char* kr = (const char*)Kt + (jt * 32 + l31) * 128;
#pragma unroll
    for (int ks = 0; ks < 4; ++ks) {
      bf16x8 kf = *(const bf16x8*)(kr + ((ks * 32 + hi * 16) ^ swz));
      s[jt] = __builtin_amdgcn_mfma_f32_32x32x16_bf16(kf, qf[ks], s[jt], 0, 0, 0);
    }
  }
  __builtin_amdgcn_s_setprio(0);

  // softmax over j (128 in-lane values; partner half has the other 128)
  float mx = -3.4e38f;
#pragma unroll
  for (int jt = 0; jt < 8; ++jt)
#pragma unroll
    for (int r = 0; r < 16; ++r) mx = fmaxf(mx, s[jt][r]);
  mx = fmaxf(mx, __shfl_xor(mx, 32, 64));
  float sum = 0.f;
#pragma unroll
  for (int jt = 0; jt < 8; ++jt)
#pragma unroll
    for (int r = 0; r < 16; ++r) {
      float p = __expf(s[jt][r] - mx);
      s[jt][r] = p; sum += p;
    }
  sum += __shfl_xor(sum, 32, 64);
  float inv = 1.f / sum;

  // P fragments (A-operand for PV), normalized, in-register regroup
  bf16x8 pf[16];
#pragma unroll
  for (int jt = 0; jt < 8; ++jt)
#pragma unroll
    for (int kb = 0; kb < 2; ++kb) {
      int kt2 = jt * 2 + kb;
      unsigned pA0 = cvtpk(s[jt][kb * 8 + 0] * inv, s[jt][kb * 8 + 1] * inv);
      unsigned pA1 = cvtpk(s[jt][kb * 8 + 2] * inv, s[jt][kb * 8 + 3] * inv);
      unsigned pB0 = cvtpk(s[jt][kb * 8 + 4] * inv, s[jt][kb * 8 + 5] * inv);
      unsigned pB1 = cvtpk(s[jt][kb * 8 + 6] * inv, s[jt][kb * 8 + 7] * inv);
      unsigned s0 = hi ? pA0 : pB0;
      unsigned s1 = hi ? pA1 : pB1;
      unsigned r0 = (unsigned)__shfl_xor((int)s0, 32, 64);
      unsigned r1 = (unsigned)__shfl_xor((int)s1, 32, 64);
      union { unsigned u[4]; bf16x8 v; } pk_;
      pk_.u[0] = hi ? r0 : pA0;
      pk_.u[1] = hi ? r1 : pA1;
      pk_.u[2] = hi ? pB0 : r0;
      pk_.u[3] = hi ? pB1 : r1;
      pf[kt2] = pk_.v;
    }

  // PV: O^T[i][d]
  f32x16 o[2] = {};
  __builtin_amdgcn_s_setprio(1);
#pragma unroll
  for (int dt = 0; dt < 2; ++dt) {
    const char* vr = (const char*)Vn + (dt * 32 + l31) * 512;
#pragma unroll
    for (int kt2 = 0; kt2 < 16; ++kt2) {
      bf16x8 vf = *(const bf16x8*)(vr + ((kt2 * 32 + hi * 16) ^ swz));
      o[dt] = __builtin_amdgcn_mfma_f32_32x32x16_bf16(pf[kt2], vf, o[dt], 0, 0, 0);
    }
  }
  __builtin_amdgcn_s_setprio(0);

  // epilogue: lane(hi, d=dt*32+l31) holds O^T[i = q*8 + hi*4 + m][d], reg 4q+m
  if (!IS_COL) {
    const unsigned short* Xr = smem + 57344;   // [256 rows][64 ch] linear
#pragma unroll
    for (int dt = 0; dt < 2; ++dt) {
      int dcol = dt * 32 + l31;
      int c = h * 64 + dcol;
      unsigned short* ob = outnat + (size_t)c * NPIX + pixbase + i0w;
#pragma unroll
      for (int q = 0; q < 4; ++q) {
        int ib = q * 8 + hi * 4;
        float4 vv;
        vv.x = o[dt][q * 4 + 0] + bf2f(Xr[(i0w + ib + 0) * 64 + dcol]);
        vv.y = o[dt][q * 4 + 1] + bf2f(Xr[(i0w + ib + 1) * 64 + dcol]);
        vv.z = o[dt][q * 4 + 2] + bf2f(Xr[(i0w + ib + 2) * 64 + dcol]);
        vv.w = o[dt][q * 4 + 3] + bf2f(Xr[(i0w + ib + 3) * 64 + dcol]);
        ushort4 pk;
        pk.x = f2bf(vv.x); pk.y = f2bf(vv.y); pk.z = f2bf(vv.z); pk.w = f2bf(vv.w);
        *(ushort4*)(ob + ib) = pk;
        o[dt][q * 4 + 0] = vv.x; o[dt][q * 4 + 1] = vv.y;
        o[dt][q * 4 + 2] = vv.z; o[dt][q * 4 + 3] = vv.w;
      }
    }
    __syncthreads();                       // qkv reads done -> overlay Obt
    unsigned short* Obt = smem;            // [256 i][72 d]
#pragma unroll
    for (int dt = 0; dt < 2; ++dt) {
      int d = dt * 32 + l31;
#pragma unroll
      for (int q = 0; q < 4; ++q)
#pragma unroll
        for (int m = 0; m < 4; ++m)
          Obt[(i0w + q * 8 + hi * 4 + m) * 72 + d] = f2bf(o[dt][q * 4 + m]);
    }
    __syncthreads();
    int row = tid >> 1, half = tid & 1;
    const unsigned short* src = Obt + row * 72 + half * 32;
    unsigned short* dst = outbt + ((size_t)row * 256 + fix) * 512 + h * 64 + half * 32;
#pragma unroll
    for (int c4 = 0; c4 < 4; ++c4)
      *(uint4*)(dst + c4 * 8) = *(const uint4*)(src + c4 * 8);
  } else {
#pragma unroll
    for (int dt = 0; dt < 2; ++dt) {
      int c = h * 64 + dt * 32 + l31;
      unsigned short* ob = outnat + (size_t)c * NPIX + pixbase + i0w;
#pragma unroll
      for (int q = 0; q < 4; ++q) {
        ushort4 pkv;
        pkv.x = f2bf(o[dt][q * 4 + 0]);
        pkv.y = f2bf(o[dt][q * 4 + 1]);
        pkv.z = f2bf(o[dt][q * 4 + 2]);
        pkv.w = f2bf(o[dt][q * 4 + 3]);
        *(ushort4*)(ob + q * 8 + hi * 4) = pkv;
      }
    }
  }
}

// --------- final: out[c][s][l] = bf2f(out1nat) + colout_bt[c][l][s] ---------
__global__ __launch_bounds__(256) void k_final(const unsigned short* __restrict__ colt,
                                               const unsigned short* __restrict__ out1nat,
                                               float* __restrict__ out) {
  __shared__ unsigned short Xs[64 * 68];
  int c = blockIdx.y;
  int lt = blockIdx.x & 3, st = blockIdx.x >> 2;
  int l0 = lt * 64, s0 = st * 64;
  int t = threadIdx.x;
  for (int rep = 0; rep < 4; ++rep) {
    int f = rep * 256 + t, li = f >> 4, jj = f & 15;
    ushort4 v = *(const ushort4*)(colt + (size_t)c * NPIX + (size_t)(l0 + li) * 256 + s0 + jj * 4);
    *(ushort4*)(Xs + li * 68 + jj * 4) = v;
  }
  __syncthreads();
  int si = t >> 2, q = t & 3;
  size_t rowoff = (size_t)c * NPIX + (size_t)(s0 + si) * 256 + l0 + q * 16;
  float* drow = out + rowoff;
  for (int h4 = 0; h4 < 4; ++h4) {
    ushort4 nv = *(const ushort4*)(out1nat + rowoff + h4 * 4);
    float4 a;
    a.x = bf2f(nv.x) + bf2f(Xs[(q * 16 + h4 * 4 + 0) * 68 + si]);
    a.y = bf2f(nv.y) + bf2f(Xs[(q * 16 + h4 * 4 + 1) * 68 + si]);
    a.z = bf2f(nv.z) + bf2f(Xs[(q * 16 + h4 * 4 + 2) * 68 + si]);
    a.w = bf2f(nv.w) + bf2f(Xs[(q * 16 + h4 * 4 + 3) * 68 + si]);
    *(float4*)(drow + h4 * 4) = a;
  }
}

extern "C" void kernel_launch(void* const* d_in, const int* in_sizes, int n_in,
                              void* d_out, int out_size, void* d_ws, size_t ws_size,
                              hipStream_t stream) {
  const float* x  = (const float*)d_in[0];
  const float* Wr = (const float*)d_in[1];
  const float* br = (const float*)d_in[2];
  const float* Wc = (const float*)d_in[3];
  const float* bc = (const float*)d_in[4];
  float* out = (float*)d_out;
  char* ws = (char*)d_ws;
  unsigned short* xT     = (unsigned short*)(ws);                        // 64 MB [p][c]
  unsigned short* o1bt   = (unsigned short*)(ws + 67108864);             // 64 MB [l*256+s][c]
  unsigned short* colout = (unsigned short*)(ws + 134217728);            // 64 MB [c][l*256+s]
  unsigned short* o1nat  = (unsigned short*)(ws + 201326592);            // 64 MB [c][s*256+l]
  unsigned short* Wrb    = (unsigned short*)(ws + 268435456);            // 1.5 MB
  unsigned short* Wcb    = (unsigned short*)(ws + 270008320);            // 1.5 MB

  k_cvt2<<<1536, 256, 0, stream>>>(Wr, Wc, Wrb, Wcb, 196608);
  k_cvt_transpose<<<dim3(1024, 8), 256, 0, stream>>>(x, xT);
  // row side: fix = s, queries i = l; out1 = x + rowO (residual from LDS xT)
  k_fused<0><<<dim3(8, 256), 512, 0, stream>>>(xT, Wrb, br, o1nat, o1bt);
  // col side: fix = l, queries i = s; panel = out1^T (pixel order l*256+s)
  k_fused<1><<<dim3(8, 256), 512, 0, stream>>>(o1bt, Wcb, bc, colout, nullptr);
  k_final<<<dim3(16, 512), 256, 0, stream>>>(colout, o1nat, out);
}